// Round 3
// baseline (164.543 us; speedup 1.0000x reference)
//
#include <hip/hip_runtime.h>
#include <math.h>

// Problem constants (match reference)
#define NB 16
#define NC 512
#define NL 8192
#define KW 7

// Fused single-pass tiling
#define TILE 64                        // columns loaded per block (incl. halo)
#define HALO (KW / 2)                  // 3
#define TIN  (TILE - 2 * HALO)         // 58 interior (written) columns
#define NTILES ((NL + TIN - 1) / TIN)  // 142
#define CG  16                         // channel groups
#define CPT (NC / CG)                  // 32 channels per thread, held in VGPRs

// ---------------------------------------------------------------------------
// One block = (batch b, column tile t). 1024 threads = 64 columns x 16
// channel-groups. Each thread loads its 32-channel slice of one column into
// registers (read x ONCE), partial max/sum -> LDS -> cross-group reduce ->
// pooled max/avg per column -> 7-tap conv + sigmoid from LDS -> multiply the
// register-held x slice and write out.
//
// CRITICAL: x is const __restrict__, so its loads are "invariant" and the
// compiler will happily rematerialize (re-load) them in the epilogue to cut
// register pressure across the barriers (round 2: VGPR_Count=28, BW 3 TB/s).
// The asm keep-alive below makes each loaded value opaque, forcing it to
// stay resident in a VGPR across both __syncthreads().
// ---------------------------------------------------------------------------
__global__ __launch_bounds__(1024) void sam1d_fused(
    const float* __restrict__ x, const float* __restrict__ w,
    float* __restrict__ out) {
    __shared__ float lds_mx[CG * TILE];
    __shared__ float lds_sm[CG * TILE];
    __shared__ float pool_mx[TILE];
    __shared__ float pool_av[TILE];

    const int tid  = threadIdx.x;
    const int lcol = tid & (TILE - 1);
    const int cg   = tid >> 6;                 // 0..15
    const int blk  = blockIdx.x;
    const int b    = blk / NTILES;
    const int t    = blk - b * NTILES;
    const int l    = t * TIN - HALO + lcol;    // global column
    const bool lvalid = (l >= 0) && (l < NL);

    const float* px = x + (size_t)b * NC * NL + (size_t)(cg * CPT) * NL + l;

    float xv[CPT];
    if (lvalid) {
#pragma unroll
        for (int j = 0; j < CPT; ++j) xv[j] = px[(size_t)j * NL];
    } else {
#pragma unroll
        for (int j = 0; j < CPT; ++j) xv[j] = 0.0f;
    }

    // per-thread partial pooling over 32 channels
    float mx = xv[0], sm = xv[0];
#pragma unroll
    for (int j = 1; j < CPT; ++j) { mx = fmaxf(mx, xv[j]); sm += xv[j]; }

    // Pin xv[] into VGPRs: opaque asm output cannot be rematerialized, so
    // the compiler cannot sink the x loads past the barriers (see header).
#pragma unroll
    for (int j = 0; j < CPT; ++j) asm volatile("" : "+v"(xv[j]));

    lds_mx[cg * TILE + lcol] = mx;
    lds_sm[cg * TILE + lcol] = sm;
    __syncthreads();

    // cross-group reduction: 64 threads do max, 64 do sum (conflict-free,
    // stride TILE=64 floats between iterations, consecutive within a wave)
    if (tid < TILE) {
        float m = lds_mx[tid];
#pragma unroll
        for (int g = 1; g < CG; ++g) m = fmaxf(m, lds_mx[g * TILE + tid]);
        const int gl = t * TIN - HALO + tid;
        pool_mx[tid] = (gl >= 0 && gl < NL) ? m : 0.0f;  // conv zero-padding
    } else if (tid < 2 * TILE) {
        const int c = tid - TILE;
        float s = lds_sm[c];
#pragma unroll
        for (int g = 1; g < CG; ++g) s += lds_sm[g * TILE + c];
        const int gl = t * TIN - HALO + c;
        pool_av[c] = (gl >= 0 && gl < NL) ? s * (1.0f / (float)NC) : 0.0f;
    }
    __syncthreads();

    // interior columns: conv (cross-correlation, no flip) + sigmoid + apply
    if (lcol >= HALO && lcol < HALO + TIN && l < NL) {
        float logit = 0.0f;
#pragma unroll
        for (int k = 0; k < KW; ++k) {
            logit = fmaf(pool_mx[lcol - HALO + k], w[k],      logit);
            logit = fmaf(pool_av[lcol - HALO + k], w[KW + k], logit);
        }
        const float attn = 1.0f / (1.0f + expf(-logit));
        float* po = out + (size_t)b * NC * NL + (size_t)(cg * CPT) * NL + l;
#pragma unroll
        for (int j = 0; j < CPT; ++j) po[(size_t)j * NL] = attn * xv[j];
    }
}

extern "C" void kernel_launch(void* const* d_in, const int* in_sizes, int n_in,
                              void* d_out, int out_size, void* d_ws, size_t ws_size,
                              hipStream_t stream) {
    const float* x = (const float*)d_in[0];
    // d_in[1] = mask — intentionally unused (reference discards masked_fill).
    const float* w = (const float*)d_in[2];   // flat (1,2,7): [0..6]=max taps, [7..13]=avg taps
    float* out = (float*)d_out;

    const int blocks = NB * NTILES;  // 16 * 142 = 2272
    sam1d_fused<<<blocks, 1024, 0, stream>>>(x, w, out);
}

// Round 4
// 146.076 us; speedup vs baseline: 1.1264x; 1.1264x over previous
//
#include <hip/hip_runtime.h>
#include <math.h>

// Problem constants (match reference)
#define NB 16
#define NC 512
#define NL 8192
#define KW 7

// Tiling: 64-col tiles overlapping by 8 so that BOTH the float4 loads
// (base-4 + 4*f4col) and the float4 stores (interior cols 4..59) are
// 16B-aligned. TIN=56 written cols per tile.
#define TILE 64
#define TIN  56
#define NTILES ((NL + TIN - 1) / TIN)  // 147
#define NF4  16                        // float4-columns per tile
#define CG   64                        // channel groups
#define CPT  8                         // channels per thread

// ---------------------------------------------------------------------------
// One block = (b, tile). 1024 threads = 16 float4-cols x 64 channel-groups.
// Each thread float4-loads its 8-channel x 4-col slice (read x once, 16B/lane
// -> 1KB/wave-instruction), partial max/sum per column -> LDS [64][65]
// (padded, <=2-way) -> 128 threads reduce over 64 groups -> pooled max/avg ->
// 7-tap conv + sigmoid -> float4 stores of attn * (register-held x).
//
// Round-2/3 lesson: x loads are invariant and get rematerialized across the
// barriers unless pinned (asm below). Round-3 lesson: traffic was already
// minimal; the 3 TB/s cap correlates with 4B/lane accesses (256B/request) --
// this version moves 16B/lane on every global access.
// ---------------------------------------------------------------------------
__global__ __launch_bounds__(1024) void sam1d_fused(
    const float* __restrict__ x, const float* __restrict__ w,
    float* __restrict__ out) {
    __shared__ float lds_mx[CG][TILE + 1];
    __shared__ float lds_sm[CG][TILE + 1];
    __shared__ float pool_mx[TILE];
    __shared__ float pool_av[TILE];

    const int tid  = threadIdx.x;
    const int f4   = tid & (NF4 - 1);          // 0..15
    const int cg   = tid >> 4;                 // 0..63
    const int b    = blockIdx.x / NTILES;
    const int t    = blockIdx.x - b * NTILES;
    const int base = t * TIN;                  // first written column
    const int c0   = base - 4 + 4 * f4;        // thread's first column (16B-aligned)
    const bool valid = (c0 >= 0) && (c0 < NL); // aligned => all-or-nothing per float4

    const float* px = x + ((size_t)b * NC + (size_t)cg * CPT) * NL + c0;

    float4 xv[CPT];
    if (valid) {
#pragma unroll
        for (int j = 0; j < CPT; ++j)
            xv[j] = *(const float4*)(px + (size_t)j * NL);
    } else {
#pragma unroll
        for (int j = 0; j < CPT; ++j) xv[j] = make_float4(0.f, 0.f, 0.f, 0.f);
    }

    // partial pool over this thread's 8 channels, per column (x,y,z,w)
    float4 mx = xv[0], sm = xv[0];
#pragma unroll
    for (int j = 1; j < CPT; ++j) {
        mx.x = fmaxf(mx.x, xv[j].x); sm.x += xv[j].x;
        mx.y = fmaxf(mx.y, xv[j].y); sm.y += xv[j].y;
        mx.z = fmaxf(mx.z, xv[j].z); sm.z += xv[j].z;
        mx.w = fmaxf(mx.w, xv[j].w); sm.w += xv[j].w;
    }

    // Pin xv[] in VGPRs so the (invariant) x loads can't be sunk/remat'd
    // past the barriers.
#pragma unroll
    for (int j = 0; j < CPT; ++j)
        asm volatile("" : "+v"(xv[j].x), "+v"(xv[j].y), "+v"(xv[j].z), "+v"(xv[j].w));

    const int lc = 4 * f4;
    lds_mx[cg][lc + 0] = mx.x;  lds_sm[cg][lc + 0] = sm.x;
    lds_mx[cg][lc + 1] = mx.y;  lds_sm[cg][lc + 1] = sm.y;
    lds_mx[cg][lc + 2] = mx.z;  lds_sm[cg][lc + 2] = sm.z;
    lds_mx[cg][lc + 3] = mx.w;  lds_sm[cg][lc + 3] = sm.w;
    __syncthreads();

    // cross-group reduction: threads 0..63 max, 64..127 sum (consecutive
    // lanes -> consecutive banks; row pad 65 keeps group-stride conflict-free)
    if (tid < TILE) {
        float m = lds_mx[0][tid];
#pragma unroll
        for (int g = 1; g < CG; ++g) m = fmaxf(m, lds_mx[g][tid]);
        const int gl = base - 4 + tid;
        pool_mx[tid] = (gl >= 0 && gl < NL) ? m : 0.0f;   // conv zero-padding
    } else if (tid < 2 * TILE) {
        const int c = tid - TILE;
        float s = lds_sm[0][c];
#pragma unroll
        for (int g = 1; g < CG; ++g) s += lds_sm[g][c];
        const int gl = base - 4 + c;
        pool_av[c] = (gl >= 0 && gl < NL) ? s * (1.0f / (float)NC) : 0.0f;
    }
    __syncthreads();

    // interior float4-columns: conv (cross-correlation) + sigmoid + apply
    if (f4 >= 1 && f4 <= 14 && c0 < NL) {
        float attn[4];
#pragma unroll
        for (int q = 0; q < 4; ++q) {
            float logit = 0.0f;
#pragma unroll
            for (int k = 0; k < KW; ++k) {
                logit = fmaf(pool_mx[lc + q + k - 3], w[k],      logit);
                logit = fmaf(pool_av[lc + q + k - 3], w[KW + k], logit);
            }
            attn[q] = 1.0f / (1.0f + expf(-logit));
        }
        float* po = out + ((size_t)b * NC + (size_t)cg * CPT) * NL + c0;
#pragma unroll
        for (int j = 0; j < CPT; ++j) {
            float4 o;
            o.x = attn[0] * xv[j].x;
            o.y = attn[1] * xv[j].y;
            o.z = attn[2] * xv[j].z;
            o.w = attn[3] * xv[j].w;
            *(float4*)(po + (size_t)j * NL) = o;
        }
    }
}

extern "C" void kernel_launch(void* const* d_in, const int* in_sizes, int n_in,
                              void* d_out, int out_size, void* d_ws, size_t ws_size,
                              hipStream_t stream) {
    const float* x = (const float*)d_in[0];
    // d_in[1] = mask — intentionally unused (reference discards masked_fill).
    const float* w = (const float*)d_in[2];   // flat (1,2,7): [0..6]=max taps, [7..13]=avg taps
    float* out = (float*)d_out;

    const int blocks = NB * NTILES;  // 16 * 147 = 2352
    sam1d_fused<<<blocks, 1024, 0, stream>>>(x, w, out);
}